// Round 1
// baseline (1311.736 us; speedup 1.0000x reference)
//
#include <hip/hip_runtime.h>
#include <hip/hip_bf16.h>

typedef __hip_bfloat16 bf16;

#define B_ 4
#define C_ 256
#define N_ 16384
#define HEADS_ 8
#define D_ 64

// LDS row stride: 68 floats = 272 B -> 16B-aligned rows (ds_read_b128 on
// contiguous 4-float reads) and (68 % 32)==4 -> worst aliasing is 2-way,
// which is free on gfx950 (m136).
#define LS 68

__global__ __launch_bounds__(256) void zero_kernel(float* __restrict__ p, int n) {
    int i = blockIdx.x * 256 + threadIdx.x;
    if (i < n) p[i] = 0.f;
}

// ---------------------------------------------------------------------------
// K1: fused QKV projection + bias + LayerNorm(dim) [+ scaled softmax(dim) for q]
// grid: (24 sections = {q,k,v} x 8 heads, N/64, B), block 256.
// Each block: GEMM 64x64x256 -> per-column (position) LN over the 64 rows ->
// q: softmax over rows -> write bf16.
// ---------------------------------------------------------------------------
__global__ __launch_bounds__(256) void qkv_kernel(
    const float* __restrict__ x,
    const float* __restrict__ wq, const float* __restrict__ bq,
    const float* __restrict__ wk, const float* __restrict__ bk,
    const float* __restrict__ wv, const float* __restrict__ bv,
    const float* __restrict__ gq, const float* __restrict__ beq,
    const float* __restrict__ gk, const float* __restrict__ bek,
    const float* __restrict__ gv, const float* __restrict__ bev,
    bf16* __restrict__ qbuf, bf16* __restrict__ kbuf, bf16* __restrict__ vbuf)
{
    __shared__ float WS[64 * LS];
    __shared__ float XS[64 * LS];
    __shared__ float OUTS[64 * LS];
    __shared__ float red0[64];
    __shared__ float red1[64];

    const int tid  = threadIdx.x;
    const int sec  = blockIdx.x;       // 0..23
    const int h    = sec & 7;
    const int kind = sec >> 3;         // 0=q 1=k 2=v
    const int n0   = blockIdx.y * 64;
    const int b    = blockIdx.z;

    const float *W, *bias, *g, *be;
    bf16* outb;
    if (kind == 0)      { W = wq; bias = bq; g = gq; be = beq; outb = qbuf; }
    else if (kind == 1) { W = wk; bias = bk; g = gk; be = bek; outb = kbuf; }
    else                { W = wv; bias = bv; g = gv; be = bev; outb = vbuf; }
    const int row0 = h * 64;

    const int ty = tid >> 4;   // 0..15 -> output rows ty*4..ty*4+3 (dims)
    const int tx = tid & 15;   // 0..15 -> output cols tx*4..tx*4+3 (positions)

    float acc[4][4];
#pragma unroll
    for (int i = 0; i < 4; i++)
#pragma unroll
        for (int j = 0; j < 4; j++) acc[i][j] = 0.f;

    for (int kc = 0; kc < 4; kc++) {
        // stage W chunk [64 rows][64 k]
        for (int i = tid; i < 4096; i += 256) {
            int r = i >> 6, k = i & 63;
            WS[r * LS + k] = W[(size_t)(row0 + r) * C_ + kc * 64 + k];
        }
        // stage X chunk [64 k][64 n]
        for (int i = tid; i < 4096; i += 256) {
            int k = i >> 6, n = i & 63;
            XS[k * LS + n] = x[((size_t)b * C_ + kc * 64 + k) * N_ + n0 + n];
        }
        __syncthreads();
        for (int kk = 0; kk < 64; kk++) {
            float av[4], bvv[4];
#pragma unroll
            for (int i = 0; i < 4; i++) av[i] = WS[(ty * 4 + i) * LS + kk];
#pragma unroll
            for (int j = 0; j < 4; j++) bvv[j] = XS[kk * LS + tx * 4 + j];
#pragma unroll
            for (int i = 0; i < 4; i++)
#pragma unroll
                for (int j = 0; j < 4; j++) acc[i][j] += av[i] * bvv[j];
        }
        __syncthreads();
    }

    // bias + per-row LN params
    float br[4], gr[4], ber[4];
#pragma unroll
    for (int i = 0; i < 4; i++) {
        int r = ty * 4 + i;
        br[i]  = bias[row0 + r];
        gr[i]  = g[r];
        ber[i] = be[r];
    }
#pragma unroll
    for (int i = 0; i < 4; i++)
#pragma unroll
        for (int j = 0; j < 4; j++) acc[i][j] += br[i];

    // column stats (LN over the 64 dim-rows per position)
#pragma unroll
    for (int i = 0; i < 4; i++)
#pragma unroll
        for (int j = 0; j < 4; j++)
            OUTS[(ty * 4 + i) * LS + tx * 4 + j] = acc[i][j];
    __syncthreads();
    if (tid < 64) {
        float s = 0.f, s2 = 0.f;
        for (int r = 0; r < 64; r++) {
            float v = OUTS[r * LS + tid];
            s += v; s2 += v * v;
        }
        float mu  = s * (1.f / 64.f);
        float var = s2 * (1.f / 64.f) - mu * mu;
        red0[tid] = mu;
        red1[tid] = rsqrtf(var + 1e-5f);
    }
    __syncthreads();

    float z[4][4];
#pragma unroll
    for (int i = 0; i < 4; i++)
#pragma unroll
        for (int j = 0; j < 4; j++) {
            int cc = tx * 4 + j;
            z[i][j] = (acc[i][j] - red0[cc]) * red1[cc] * gr[i] + ber[i];
        }

    if (kind == 0) {
        // q: softmax over the 64 dim-rows of (z * KD^-0.25)
        const float s_q = 0.35355339059327373f;  // 64^-0.25
#pragma unroll
        for (int i = 0; i < 4; i++)
#pragma unroll
            for (int j = 0; j < 4; j++) z[i][j] *= s_q;
        __syncthreads();
#pragma unroll
        for (int i = 0; i < 4; i++)
#pragma unroll
            for (int j = 0; j < 4; j++)
                OUTS[(ty * 4 + i) * LS + tx * 4 + j] = z[i][j];
        __syncthreads();
        if (tid < 64) {
            float m = -1e30f, d = 0.f;
            for (int r = 0; r < 64; r++) {
                float v = OUTS[r * LS + tid];
                float nm = fmaxf(m, v);
                d = d * __expf(m - nm) + __expf(v - nm);
                m = nm;
            }
            red0[tid] = m;
            red1[tid] = 1.f / d;
        }
        __syncthreads();
#pragma unroll
        for (int i = 0; i < 4; i++)
#pragma unroll
            for (int j = 0; j < 4; j++) {
                int cc = tx * 4 + j;
                z[i][j] = __expf(z[i][j] - red0[cc]) * red1[cc];
            }
    }

    // store bf16
#pragma unroll
    for (int i = 0; i < 4; i++) {
        int r = row0 + ty * 4 + i;
#pragma unroll
        for (int j = 0; j < 4; j++) {
            int cc = n0 + tx * 4 + j;
            outb[((size_t)b * 512 + r) * N_ + cc] = __float2bfloat16(z[i][j]);
        }
    }
}

// ---------------------------------------------------------------------------
// K2: ctx partials: ctx[b,h,kd,vd] += sum_n exp(k[kd,n]) * v[vd,n]
//     plus row sums (the softmax denominator) in column 64.
// grid: (32 n-chunks of 512, HEADS, B), block 256. atomicAdd into ctx_acc.
// ---------------------------------------------------------------------------
__global__ __launch_bounds__(256) void ctx_kernel(
    const bf16* __restrict__ kbuf, const bf16* __restrict__ vbuf,
    float* __restrict__ ctx_acc)
{
    __shared__ float ES[64 * LS];
    __shared__ float VS[64 * LS];

    const int tid = threadIdx.x;
    const int ty = tid >> 4, tx = tid & 15;
    const int b = blockIdx.z, h = blockIdx.y;
    const int n0 = blockIdx.x * 512;

    const bf16* kp = kbuf + ((size_t)b * 512 + h * 64) * N_;
    const bf16* vp = vbuf + ((size_t)b * 512 + h * 64) * N_;

    float acc[4][4];
    float rowacc[4];
#pragma unroll
    for (int i = 0; i < 4; i++) {
        rowacc[i] = 0.f;
#pragma unroll
        for (int j = 0; j < 4; j++) acc[i][j] = 0.f;
    }

    for (int nb = 0; nb < 8; nb++) {
        int nn0 = n0 + nb * 64;
        for (int i = tid; i < 4096; i += 256) {
            int r = i >> 6, n = i & 63;
            ES[r * LS + n] = __expf(__bfloat162float(kp[(size_t)r * N_ + nn0 + n]));
            VS[r * LS + n] = __bfloat162float(vp[(size_t)r * N_ + nn0 + n]);
        }
        __syncthreads();
        for (int nn = 0; nn < 64; nn++) {
            float av[4], bvv[4];
#pragma unroll
            for (int i = 0; i < 4; i++) av[i] = ES[(ty * 4 + i) * LS + nn];
#pragma unroll
            for (int j = 0; j < 4; j++) bvv[j] = VS[(tx * 4 + j) * LS + nn];
#pragma unroll
            for (int i = 0; i < 4; i++)
#pragma unroll
                for (int j = 0; j < 4; j++) acc[i][j] += av[i] * bvv[j];
            if (tx == 0) {
#pragma unroll
                for (int i = 0; i < 4; i++) rowacc[i] += av[i];
            }
        }
        __syncthreads();
    }

    size_t base = (size_t)(b * 8 + h) * 64 * 65;
#pragma unroll
    for (int i = 0; i < 4; i++)
#pragma unroll
        for (int j = 0; j < 4; j++)
            atomicAdd(&ctx_acc[base + (size_t)(ty * 4 + i) * 65 + tx * 4 + j], acc[i][j]);
    if (tx == 0) {
#pragma unroll
        for (int i = 0; i < 4; i++)
            atomicAdd(&ctx_acc[base + (size_t)(ty * 4 + i) * 65 + 64], rowacc[i]);
    }
}

// ---------------------------------------------------------------------------
// K3: Weff[b][c][h*64+kd] = sum_vd wo[c, h*64+vd] * (ctx_acc[...vd]/rowsum)
// grid: (HEADS, B), block 256 (one thread per output channel c).
// ---------------------------------------------------------------------------
__global__ __launch_bounds__(256) void weff_kernel(
    const float* __restrict__ ctx_acc, const float* __restrict__ wo,
    float* __restrict__ Weff)
{
    __shared__ float CTX[64 * 65];
    const int tid = threadIdx.x;
    const int h = blockIdx.x, b = blockIdx.y;
    size_t base = (size_t)(b * 8 + h) * 64 * 65;
    for (int i = tid; i < 4096; i += 256) {
        int kd = i >> 6, vd = i & 63;
        CTX[kd * 65 + vd] = ctx_acc[base + kd * 65 + vd] / ctx_acc[base + kd * 65 + 64];
    }
    __syncthreads();
    const int c = tid;  // 0..255
    float worow[64];
#pragma unroll
    for (int vd = 0; vd < 64; vd++) worow[vd] = wo[(size_t)c * 512 + h * 64 + vd];
    for (int kd = 0; kd < 64; kd++) {
        float s = 0.f;
#pragma unroll
        for (int vd = 0; vd < 64; vd++) s += worow[vd] * CTX[kd * 65 + vd];
        Weff[((size_t)b * 256 + c) * 512 + h * 64 + kd] = s;
    }
}

// ---------------------------------------------------------------------------
// K4: y[b][c][n] = sum_r Weff[b][c][r] * q[b][r][n] + bo[c]
// grid: (N/64, 256/64, B), block 256. 64x64 tile, K=512.
// ---------------------------------------------------------------------------
__global__ __launch_bounds__(256) void out_kernel(
    const float* __restrict__ Weff, const bf16* __restrict__ qbuf,
    const float* __restrict__ bo, float* __restrict__ out)
{
    __shared__ float AS[64 * LS];
    __shared__ float BS[64 * LS];

    const int tid = threadIdx.x;
    const int ty = tid >> 4, tx = tid & 15;
    const int b = blockIdx.z;
    const int c0 = blockIdx.y * 64;
    const int n0 = blockIdx.x * 64;

    float acc[4][4];
#pragma unroll
    for (int i = 0; i < 4; i++)
#pragma unroll
        for (int j = 0; j < 4; j++) acc[i][j] = 0.f;

    for (int kc = 0; kc < 8; kc++) {
        for (int i = tid; i < 4096; i += 256) {
            int r = i >> 6, k = i & 63;
            AS[r * LS + k] = Weff[((size_t)b * 256 + c0 + r) * 512 + kc * 64 + k];
        }
        for (int i = tid; i < 4096; i += 256) {
            int k = i >> 6, n = i & 63;
            BS[k * LS + n] =
                __bfloat162float(qbuf[((size_t)b * 512 + kc * 64 + k) * N_ + n0 + n]);
        }
        __syncthreads();
        for (int kk = 0; kk < 64; kk++) {
            float av[4], bvv[4];
#pragma unroll
            for (int i = 0; i < 4; i++) av[i] = AS[(ty * 4 + i) * LS + kk];
#pragma unroll
            for (int j = 0; j < 4; j++) bvv[j] = BS[kk * LS + tx * 4 + j];
#pragma unroll
            for (int i = 0; i < 4; i++)
#pragma unroll
                for (int j = 0; j < 4; j++) acc[i][j] += av[i] * bvv[j];
        }
        __syncthreads();
    }

#pragma unroll
    for (int i = 0; i < 4; i++) {
        float bb = bo[c0 + ty * 4 + i];
#pragma unroll
        for (int j = 0; j < 4; j++)
            out[((size_t)b * 256 + c0 + ty * 4 + i) * N_ + n0 + tx * 4 + j] =
                acc[i][j] + bb;
    }
}

extern "C" void kernel_launch(void* const* d_in, const int* in_sizes, int n_in,
                              void* d_out, int out_size, void* d_ws, size_t ws_size,
                              hipStream_t stream) {
    const float* x   = (const float*)d_in[0];
    const float* wq  = (const float*)d_in[1];
    const float* bq  = (const float*)d_in[2];
    const float* wk  = (const float*)d_in[3];
    const float* bk  = (const float*)d_in[4];
    const float* wv  = (const float*)d_in[5];
    const float* bv  = (const float*)d_in[6];
    const float* wo  = (const float*)d_in[7];
    const float* bo  = (const float*)d_in[8];
    const float* gq  = (const float*)d_in[9];
    const float* beq = (const float*)d_in[10];
    const float* gk  = (const float*)d_in[11];
    const float* bek = (const float*)d_in[12];
    const float* gv  = (const float*)d_in[13];
    const float* bev = (const float*)d_in[14];
    float* out = (float*)d_out;

    char* ws = (char*)d_ws;
    // layout: qbuf/kbuf/vbuf bf16 [B][512][N] (64 MiB each), ctx_acc fp32
    // [B][H][64][65], Weff fp32 [B][256][512]
    bf16* qbuf = (bf16*)(ws);
    bf16* kbuf = (bf16*)(ws + (size_t)67108864);
    bf16* vbuf = (bf16*)(ws + (size_t)134217728);
    float* ctx_acc = (float*)(ws + (size_t)201326592);
    float* Weff    = (float*)(ws + (size_t)201326592 + 532480);

    const int nctx = B_ * HEADS_ * 64 * 65;
    zero_kernel<<<dim3((nctx + 255) / 256), 256, 0, stream>>>(ctx_acc, nctx);

    qkv_kernel<<<dim3(24, N_ / 64, B_), 256, 0, stream>>>(
        x, wq, bq, wk, bk, wv, bv, gq, beq, gk, bek, gv, bev, qbuf, kbuf, vbuf);

    ctx_kernel<<<dim3(32, HEADS_, B_), 256, 0, stream>>>(kbuf, vbuf, ctx_acc);

    weff_kernel<<<dim3(HEADS_, B_), 256, 0, stream>>>(ctx_acc, wo, Weff);

    out_kernel<<<dim3(N_ / 64, 256 / 64, B_), 256, 0, stream>>>(Weff, qbuf, bo, out);
}

// Round 2
// 511.739 us; speedup vs baseline: 2.5633x; 2.5633x over previous
//
#include <hip/hip_runtime.h>
#include <hip/hip_bf16.h>
#include <stdint.h>

typedef unsigned short u16;
typedef __attribute__((__vector_size__(16))) short s16x8;
typedef __attribute__((__vector_size__(16))) float f32x4;

#define N_ 16384
#define C_ 256
#define LSQ 72    // bf16 LDS stride for [128][64] tiles (144 B rows: 16B aligned, <=2-way banks)
#define LS2 136   // bf16 LDS stride for [64][128] tiles (272 B rows)

__device__ __forceinline__ float bf2f(u16 u) {
    union { uint32_t i; float f; } v; v.i = ((uint32_t)u) << 16; return v.f;
}
__device__ __forceinline__ u16 f2bf(float f) {
    union { uint32_t i; float f; } v; v.f = f;
    uint32_t u = v.i;
    return (u16)((u + 0x7FFFu + ((u >> 16) & 1u)) >> 16);
}

// ---------------------------------------------------------------------------
// K0: x fp32 [B][C][N] -> xT bf16 [B][N][C]
// ---------------------------------------------------------------------------
__global__ __launch_bounds__(256) void transpose_kernel(const float* __restrict__ x,
                                                        u16* __restrict__ xT) {
    __shared__ float T[64][65];
    int tid = threadIdx.x;
    int n0 = blockIdx.x * 64, c0 = blockIdx.y * 64, b = blockIdx.z;
    const float* xp = x + (size_t)b * C_ * N_;
    for (int it = 0; it < 16; it++) {
        int idx = it * 256 + tid;
        int c = idx >> 6, n = idx & 63;
        T[c][n] = xp[(size_t)(c0 + c) * N_ + n0 + n];
    }
    __syncthreads();
    u16* op = xT + (size_t)b * N_ * C_;
    for (int it = 0; it < 8; it++) {
        int idx = it * 256 + tid;
        int n = idx >> 5, c2 = (idx & 31) * 2;
        uint32_t lo = f2bf(T[c2][n]);
        uint32_t hi = f2bf(T[c2 + 1][n]);
        *(uint32_t*)&op[(size_t)(n0 + n) * C_ + c0 + c2] = lo | (hi << 16);
    }
}

// ---------------------------------------------------------------------------
// Kw: wq/wk/wv fp32 -> wb bf16 [3][512][256]
// ---------------------------------------------------------------------------
__global__ __launch_bounds__(256) void cvtw_kernel(const float* __restrict__ wq,
                                                   const float* __restrict__ wk,
                                                   const float* __restrict__ wv,
                                                   u16* __restrict__ wb) {
    int m = blockIdx.y;
    const float* s = m == 0 ? wq : (m == 1 ? wk : wv);
    int i = blockIdx.x * 256 + threadIdx.x;
    wb[(size_t)m * 131072 + i] = f2bf(s[i]);
}

// ---------------------------------------------------------------------------
// K1: fused QKV projection (MFMA) + bias + LN(dim) [+ softmax(dim) for q]
// grid (128 ntiles, 12 sections={kind(3) x rowpair(4)}), block 256 (4 waves 2x2)
// q: A=W (lane&15 -> W-row) -> packed 8B stores to qT[b][n][512]
// k/v: A=xT (lane&15 -> n)  -> packed 8B stores to kb/vb[512][N]
// ---------------------------------------------------------------------------
__global__ __launch_bounds__(256) void qkv_kernel(
    const u16* __restrict__ xT, const u16* __restrict__ wb,
    const float* __restrict__ bq, const float* __restrict__ bk, const float* __restrict__ bv,
    const float* __restrict__ gq, const float* __restrict__ beq,
    const float* __restrict__ gk, const float* __restrict__ bek,
    const float* __restrict__ gv, const float* __restrict__ bev,
    u16* __restrict__ qT, u16* __restrict__ kb, u16* __restrict__ vb, int b)
{
    __shared__ u16 WS[128 * LSQ];
    __shared__ u16 XS[128 * LSQ];
    int tid = threadIdx.x;
    int lane = tid & 63, wid = tid >> 6;
    int quad = lane >> 4, l15 = lane & 15;
    int wm = wid >> 1, wn = wid & 1;
    int sec = blockIdx.y;
    int kind = sec >> 2, pair = sec & 3;
    int r0 = pair * 128;
    int n0 = blockIdx.x * 128;

    const float* bptr  = kind == 0 ? bq  : (kind == 1 ? bk  : bv);
    const float* gptr  = kind == 0 ? gq  : (kind == 1 ? gk  : gv);
    const float* beptr = kind == 0 ? beq : (kind == 1 ? bek : bev);

    const u16* wsrc = wb + (size_t)kind * 131072 + (size_t)r0 * 256;
    const u16* xsrc = xT + ((size_t)b * N_ + n0) * 256;

    f32x4 acc[4][4];
#pragma unroll
    for (int i = 0; i < 4; i++)
#pragma unroll
        for (int j = 0; j < 4; j++) acc[i][j] = (f32x4){0.f, 0.f, 0.f, 0.f};

    const u16* aB = (kind == 0) ? (WS + wm * 64 * LSQ) : (XS + wn * 64 * LSQ);
    const u16* bB = (kind == 0) ? (XS + wn * 64 * LSQ) : (WS + wm * 64 * LSQ);

    for (int kc = 0; kc < 4; kc++) {
#pragma unroll
        for (int it = 0; it < 4; it++) {
            int idx = it * 256 + tid;
            int row = idx >> 3, k8 = (idx & 7) * 8;
            *(s16x8*)&WS[row * LSQ + k8] = *(const s16x8*)&wsrc[(size_t)row * 256 + kc * 64 + k8];
            *(s16x8*)&XS[row * LSQ + k8] = *(const s16x8*)&xsrc[(size_t)row * 256 + kc * 64 + k8];
        }
        __syncthreads();
#pragma unroll
        for (int ks = 0; ks < 2; ks++) {
            int ko = ks * 32 + quad * 8;
            s16x8 af[4], bff[4];
#pragma unroll
            for (int f = 0; f < 4; f++) {
                af[f]  = *(const s16x8*)&aB[(f * 16 + l15) * LSQ + ko];
                bff[f] = *(const s16x8*)&bB[(f * 16 + l15) * LSQ + ko];
            }
#pragma unroll
            for (int i = 0; i < 4; i++)
#pragma unroll
                for (int j = 0; j < 4; j++)
                    acc[i][j] = __builtin_amdgcn_mfma_f32_16x16x32_bf16(af[i], bff[j], acc[i][j], 0, 0, 0);
        }
        __syncthreads();
    }

    if (kind == 0) {
        // value(mf,nf,reg): row rl = mf*16+quad*4+reg (in head), col n = wn*64+nf*16+l15
        float bA[4][4], gA[4][4], eA[4][4];
#pragma unroll
        for (int mf = 0; mf < 4; mf++)
#pragma unroll
            for (int r = 0; r < 4; r++) {
                int rl = mf * 16 + quad * 4 + r;
                bA[mf][r] = bptr[r0 + wm * 64 + rl];
                gA[mf][r] = gptr[rl];
                eA[mf][r] = beptr[rl];
            }
#pragma unroll
        for (int mf = 0; mf < 4; mf++)
#pragma unroll
            for (int nf = 0; nf < 4; nf++)
#pragma unroll
                for (int r = 0; r < 4; r++) acc[mf][nf][r] += bA[mf][r];
        // LN over the 64 rows per column nf
#pragma unroll
        for (int nf = 0; nf < 4; nf++) {
            float s = 0.f, s2 = 0.f;
#pragma unroll
            for (int mf = 0; mf < 4; mf++)
#pragma unroll
                for (int r = 0; r < 4; r++) { float v = acc[mf][nf][r]; s += v; s2 += v * v; }
            s  += __shfl_xor(s, 16);  s  += __shfl_xor(s, 32);
            s2 += __shfl_xor(s2, 16); s2 += __shfl_xor(s2, 32);
            float mu = s * (1.f / 64.f);
            float rstd = rsqrtf(s2 * (1.f / 64.f) - mu * mu + 1e-5f);
#pragma unroll
            for (int mf = 0; mf < 4; mf++)
#pragma unroll
                for (int r = 0; r < 4; r++)
                    acc[mf][nf][r] = (acc[mf][nf][r] - mu) * rstd * gA[mf][r] + eA[mf][r];
        }
        // softmax over rows of z * 64^-0.25
        const float s_q = 0.35355339059327373f;
#pragma unroll
        for (int nf = 0; nf < 4; nf++) {
            float m = -1e30f;
#pragma unroll
            for (int mf = 0; mf < 4; mf++)
#pragma unroll
                for (int r = 0; r < 4; r++) { acc[mf][nf][r] *= s_q; m = fmaxf(m, acc[mf][nf][r]); }
            m = fmaxf(m, __shfl_xor(m, 16)); m = fmaxf(m, __shfl_xor(m, 32));
            float d = 0.f;
#pragma unroll
            for (int mf = 0; mf < 4; mf++)
#pragma unroll
                for (int r = 0; r < 4; r++) { float e = __expf(acc[mf][nf][r] - m); acc[mf][nf][r] = e; d += e; }
            d += __shfl_xor(d, 16); d += __shfl_xor(d, 32);
            float inv = 1.f / d;
#pragma unroll
            for (int mf = 0; mf < 4; mf++)
#pragma unroll
                for (int r = 0; r < 4; r++) acc[mf][nf][r] *= inv;
        }
        u16* qp = qT + (size_t)b * N_ * 512;
#pragma unroll
        for (int mf = 0; mf < 4; mf++)
#pragma unroll
            for (int nf = 0; nf < 4; nf++) {
                int n = n0 + wn * 64 + nf * 16 + l15;
                int g0 = r0 + wm * 64 + mf * 16 + quad * 4;
                uint64_t w0 = (uint64_t)f2bf(acc[mf][nf][0]) | ((uint64_t)f2bf(acc[mf][nf][1]) << 16) |
                              ((uint64_t)f2bf(acc[mf][nf][2]) << 32) | ((uint64_t)f2bf(acc[mf][nf][3]) << 48);
                *(uint64_t*)&qp[(size_t)n * 512 + g0] = w0;
            }
    } else {
        // value(mf,nf,reg): n = wn*64+mf*16+quad*4+reg, row rl = nf*16+l15 (in head)
        float bB_[4], gB[4], eB[4];
#pragma unroll
        for (int nf = 0; nf < 4; nf++) {
            int rl = nf * 16 + l15;
            bB_[nf] = bptr[r0 + wm * 64 + rl];
            gB[nf]  = gptr[rl];
            eB[nf]  = beptr[rl];
        }
#pragma unroll
        for (int mf = 0; mf < 4; mf++)
#pragma unroll
            for (int nf = 0; nf < 4; nf++)
#pragma unroll
                for (int r = 0; r < 4; r++) acc[mf][nf][r] += bB_[nf];
        // LN over rows (lane&15 x nf) per fixed n=(mf,reg)
        float sa[4][4], sb[4][4];
#pragma unroll
        for (int mf = 0; mf < 4; mf++)
#pragma unroll
            for (int r = 0; r < 4; r++) {
                float s = 0.f, s2 = 0.f;
#pragma unroll
                for (int nf = 0; nf < 4; nf++) { float v = acc[mf][nf][r]; s += v; s2 += v * v; }
                sa[mf][r] = s; sb[mf][r] = s2;
            }
#pragma unroll
        for (int msk = 1; msk <= 8; msk <<= 1)
#pragma unroll
            for (int mf = 0; mf < 4; mf++)
#pragma unroll
                for (int r = 0; r < 4; r++) {
                    sa[mf][r] += __shfl_xor(sa[mf][r], msk);
                    sb[mf][r] += __shfl_xor(sb[mf][r], msk);
                }
        u16* op = (kind == 1) ? kb : vb;
#pragma unroll
        for (int mf = 0; mf < 4; mf++)
#pragma unroll
            for (int r = 0; r < 4; r++) {
                float mu = sa[mf][r] * (1.f / 64.f);
                float rstd = rsqrtf(sb[mf][r] * (1.f / 64.f) - mu * mu + 1e-5f);
#pragma unroll
                for (int nf = 0; nf < 4; nf++)
                    acc[mf][nf][r] = (acc[mf][nf][r] - mu) * rstd * gB[nf] + eB[nf];
            }
#pragma unroll
        for (int mf = 0; mf < 4; mf++)
#pragma unroll
            for (int nf = 0; nf < 4; nf++) {
                int n = n0 + wn * 64 + mf * 16 + quad * 4;
                int gr = r0 + wm * 64 + nf * 16 + l15;
                uint64_t w0 = (uint64_t)f2bf(acc[mf][nf][0]) | ((uint64_t)f2bf(acc[mf][nf][1]) << 16) |
                              ((uint64_t)f2bf(acc[mf][nf][2]) << 32) | ((uint64_t)f2bf(acc[mf][nf][3]) << 48);
                *(uint64_t*)&op[(size_t)gr * N_ + n] = w0;
            }
    }
}

// ---------------------------------------------------------------------------
// K2: ctx partials via MFMA: ctx[kd][vd] = sum_n exp(k[kd,n]) v[vd,n]
// grid (32 ns, 8 h), block 256; waves split the K(n) dim; LDS reduce;
// deterministic per-ns partials (no global atomics).
// ---------------------------------------------------------------------------
__global__ __launch_bounds__(256) void ctx_kernel(
    const u16* __restrict__ kb, const u16* __restrict__ vb,
    float* __restrict__ ctx_part, float* __restrict__ rs_part, int b)
{
    __shared__ u16 ES[64 * LS2];
    __shared__ u16 VS[64 * LS2];
    __shared__ float rowsumS[64];
    __shared__ float CTXS[64 * 66];
    int tid = threadIdx.x;
    int lane = tid & 63, wid = tid >> 6;
    int quad = lane >> 4, l15 = lane & 15;
    int ns = blockIdx.x, h = blockIdx.y;
    if (tid < 64) rowsumS[tid] = 0.f;
    for (int i = tid; i < 64 * 66; i += 256) CTXS[i] = 0.f;
    __syncthreads();
    const u16* kp = kb + (size_t)(h * 64) * N_;
    const u16* vp = vb + (size_t)(h * 64) * N_;
    f32x4 acc[4][4];
#pragma unroll
    for (int i = 0; i < 4; i++)
#pragma unroll
        for (int j = 0; j < 4; j++) acc[i][j] = (f32x4){0.f, 0.f, 0.f, 0.f};

    int nb = ns * 512;
    for (int ch = 0; ch < 4; ch++) {
        int nc = nb + ch * 128;
#pragma unroll
        for (int it = 0; it < 4; it++) {
            int idx = it * 256 + tid;
            int row = idx >> 4, g8 = (idx & 15) * 8;
            s16x8 kv = *(const s16x8*)&kp[(size_t)row * N_ + nc + g8];
            s16x8 ev;
            float ssum = 0.f;
#pragma unroll
            for (int j = 0; j < 8; j++) {
                float e = __expf(bf2f((u16)kv[j]));
                ssum += e;
                ev[j] = (short)f2bf(e);
            }
            atomicAdd(&rowsumS[row], ssum);
            *(s16x8*)&ES[row * LS2 + g8] = ev;
            *(s16x8*)&VS[row * LS2 + g8] = *(const s16x8*)&vp[(size_t)row * N_ + nc + g8];
        }
        __syncthreads();
        int ko = wid * 32 + quad * 8;
        s16x8 af[4], bvf[4];
#pragma unroll
        for (int f = 0; f < 4; f++) {
            af[f]  = *(const s16x8*)&ES[(f * 16 + l15) * LS2 + ko];
            bvf[f] = *(const s16x8*)&VS[(f * 16 + l15) * LS2 + ko];
        }
#pragma unroll
        for (int i = 0; i < 4; i++)
#pragma unroll
            for (int j = 0; j < 4; j++)
                acc[i][j] = __builtin_amdgcn_mfma_f32_16x16x32_bf16(af[i], bvf[j], acc[i][j], 0, 0, 0);
        __syncthreads();
    }
#pragma unroll
    for (int mf = 0; mf < 4; mf++)
#pragma unroll
        for (int nf = 0; nf < 4; nf++)
#pragma unroll
            for (int r = 0; r < 4; r++) {
                int kd = mf * 16 + quad * 4 + r, vd = nf * 16 + l15;
                atomicAdd(&CTXS[kd * 66 + vd], acc[mf][nf][r]);
            }
    __syncthreads();
    size_t base = ((((size_t)b * 8) + h) * 32 + ns) * 4096;
    for (int i = tid; i < 4096; i += 256) ctx_part[base + i] = CTXS[(i >> 6) * 66 + (i & 63)];
    if (tid < 64) rs_part[(((size_t)b * 8 + h) * 32 + ns) * 64 + tid] = rowsumS[tid];
}

// ---------------------------------------------------------------------------
// K3: reduce partials, normalize, Weff[c][h*64+kd] = sum_vd wo[c][h*64+vd]*ctxn
// ---------------------------------------------------------------------------
__global__ __launch_bounds__(256) void weff_kernel(
    const float* __restrict__ ctx_part, const float* __restrict__ rs_part,
    const float* __restrict__ wo, u16* __restrict__ Weffb)
{
    __shared__ float CTXS[64 * 66];
    __shared__ float RS[64];
    int tid = threadIdx.x;
    int h = blockIdx.x, b = blockIdx.y;
    size_t pbase = (((size_t)b * 8) + h) * 32;
    for (int i = tid; i < 4096; i += 256) {
        float s = 0.f;
        for (int ns = 0; ns < 32; ns++) s += ctx_part[(pbase + ns) * 4096 + i];
        CTXS[(i >> 6) * 66 + (i & 63)] = s;
    }
    if (tid < 64) {
        float r = 0.f;
        for (int ns = 0; ns < 32; ns++) r += rs_part[(pbase + ns) * 64 + tid];
        RS[tid] = r;
    }
    __syncthreads();
    for (int i = tid; i < 4096; i += 256) {
        int kd = i >> 6;
        CTXS[kd * 66 + (i & 63)] /= RS[kd];
    }
    __syncthreads();
    int c = tid;
    float wrow[64];
#pragma unroll
    for (int vd = 0; vd < 64; vd++) wrow[vd] = wo[(size_t)c * 512 + h * 64 + vd];
    for (int kd = 0; kd < 64; kd++) {
        float s = 0.f;
#pragma unroll
        for (int vd = 0; vd < 64; vd++) s += wrow[vd] * CTXS[kd * 66 + vd];
        Weffb[((size_t)b * 256 + c) * 512 + h * 64 + kd] = f2bf(s);
    }
}

// ---------------------------------------------------------------------------
// K4: out[c][n] = sum_r Weff[c][r] qT[n][r] + bo[c]   (MFMA, K=512)
// grid (128 nt, 2 ct, 4 b), block 256 (2x2 waves of 64x64)
// ---------------------------------------------------------------------------
__global__ __launch_bounds__(256) void out_kernel(
    const u16* __restrict__ Weffb, const u16* __restrict__ qT,
    const float* __restrict__ bo, float* __restrict__ out)
{
    __shared__ u16 WS[128 * LSQ];
    __shared__ u16 XS[128 * LSQ];
    int tid = threadIdx.x;
    int lane = tid & 63, wid = tid >> 6;
    int quad = lane >> 4, l15 = lane & 15;
    int wm = wid >> 1, wn = wid & 1;
    int n0 = blockIdx.x * 128, c0 = blockIdx.y * 128, b = blockIdx.z;
    const u16* asrc = Weffb + ((size_t)b * 256 + c0) * 512;
    const u16* bsrc = qT + ((size_t)b * N_ + n0) * 512;

    f32x4 acc[4][4];
#pragma unroll
    for (int i = 0; i < 4; i++)
#pragma unroll
        for (int j = 0; j < 4; j++) acc[i][j] = (f32x4){0.f, 0.f, 0.f, 0.f};

    for (int kc = 0; kc < 8; kc++) {
#pragma unroll
        for (int it = 0; it < 4; it++) {
            int idx = it * 256 + tid;
            int row = idx >> 3, k8 = (idx & 7) * 8;
            *(s16x8*)&WS[row * LSQ + k8] = *(const s16x8*)&asrc[(size_t)row * 512 + kc * 64 + k8];
            *(s16x8*)&XS[row * LSQ + k8] = *(const s16x8*)&bsrc[(size_t)row * 512 + kc * 64 + k8];
        }
        __syncthreads();
#pragma unroll
        for (int ks = 0; ks < 2; ks++) {
            int ko = ks * 32 + quad * 8;
            s16x8 af[4], bqf[4];
#pragma unroll
            for (int f = 0; f < 4; f++) {
                af[f]  = *(const s16x8*)&WS[(wm * 64 + f * 16 + l15) * LSQ + ko];
                bqf[f] = *(const s16x8*)&XS[(wn * 64 + f * 16 + l15) * LSQ + ko];
            }
#pragma unroll
            for (int i = 0; i < 4; i++)
#pragma unroll
                for (int j = 0; j < 4; j++)
                    acc[i][j] = __builtin_amdgcn_mfma_f32_16x16x32_bf16(af[i], bqf[j], acc[i][j], 0, 0, 0);
        }
        __syncthreads();
    }
#pragma unroll
    for (int mf = 0; mf < 4; mf++)
#pragma unroll
        for (int r = 0; r < 4; r++) {
            int c = c0 + wm * 64 + mf * 16 + quad * 4 + r;
            float bov = bo[c];
#pragma unroll
            for (int nf = 0; nf < 4; nf++)
                out[((size_t)b * 256 + c) * N_ + n0 + wn * 64 + nf * 16 + l15] = acc[mf][nf][r] + bov;
        }
}

extern "C" void kernel_launch(void* const* d_in, const int* in_sizes, int n_in,
                              void* d_out, int out_size, void* d_ws, size_t ws_size,
                              hipStream_t stream) {
    const float* x   = (const float*)d_in[0];
    const float* wq  = (const float*)d_in[1];
    const float* bq  = (const float*)d_in[2];
    const float* wk  = (const float*)d_in[3];
    const float* bk  = (const float*)d_in[4];
    const float* wv  = (const float*)d_in[5];
    const float* bv  = (const float*)d_in[6];
    const float* wo  = (const float*)d_in[7];
    const float* bo  = (const float*)d_in[8];
    const float* gq  = (const float*)d_in[9];
    const float* beq = (const float*)d_in[10];
    const float* gk  = (const float*)d_in[11];
    const float* bek = (const float*)d_in[12];
    const float* gv  = (const float*)d_in[13];
    const float* bev = (const float*)d_in[14];
    float* out = (float*)d_out;

    char* ws = (char*)d_ws;
    u16* xT       = (u16*)(ws);                          // 33,554,432
    u16* wb       = (u16*)(ws + 33554432ULL);            //    786,432
    u16* qT       = (u16*)(ws + 34340864ULL);            // 67,108,864
    u16* kbuf     = (u16*)(ws + 101449728ULL);           // 16,777,216 (per-batch)
    u16* vbuf     = (u16*)(ws + 118226944ULL);           // 16,777,216 (per-batch)
    float* ctx_p  = (float*)(ws + 135004160ULL);         // 16,777,216
    float* rs_p   = (float*)(ws + 151781376ULL);         //    262,144
    u16* Weffb    = (u16*)(ws + 152043520ULL);           //  1,048,576

    cvtw_kernel<<<dim3(512, 3), 256, 0, stream>>>(wq, wk, wv, wb);
    transpose_kernel<<<dim3(256, 4, 4), 256, 0, stream>>>(x, xT);
    for (int b = 0; b < 4; b++) {
        qkv_kernel<<<dim3(128, 12), 256, 0, stream>>>(
            xT, wb, bq, bk, bv, gq, beq, gk, bek, gv, bev, qT, kbuf, vbuf, b);
        ctx_kernel<<<dim3(32, 8), 256, 0, stream>>>(kbuf, vbuf, ctx_p, rs_p, b);
    }
    weff_kernel<<<dim3(8, 4), 256, 0, stream>>>(ctx_p, rs_p, wo, Weffb);
    out_kernel<<<dim3(128, 2, 4), 256, 0, stream>>>(Weffb, qT, bo, out);
}

// Round 3
// 479.940 us; speedup vs baseline: 2.7331x; 1.0663x over previous
//
#include <hip/hip_runtime.h>
#include <hip/hip_bf16.h>
#include <stdint.h>

typedef unsigned short u16;
typedef __attribute__((__vector_size__(16))) short s16x8;
typedef __attribute__((__vector_size__(16))) float f32x4;

#define N_ 16384
#define C_ 256
#define LSQ 72    // bf16 LDS stride for [128][64] tiles
#define LS2 136   // bf16 LDS stride for [64][128] tiles

__device__ __forceinline__ float bf2f(u16 u) {
    union { uint32_t i; float f; } v; v.i = ((uint32_t)u) << 16; return v.f;
}
__device__ __forceinline__ u16 f2bf(float f) {
    union { uint32_t i; float f; } v; v.f = f;
    uint32_t u = v.i;
    return (u16)((u + 0x7FFFu + ((u >> 16) & 1u)) >> 16);
}

__global__ __launch_bounds__(256) void zero_kernel(float* __restrict__ p, int n) {
    int i = blockIdx.x * 256 + threadIdx.x;
    if (i < n) p[i] = 0.f;
}

// ---------------------------------------------------------------------------
// K0: x fp32 [B][C][N] -> xT bf16 [B][N][C]
// ---------------------------------------------------------------------------
__global__ __launch_bounds__(256) void transpose_kernel(const float* __restrict__ x,
                                                        u16* __restrict__ xT) {
    __shared__ float T[64][65];
    int tid = threadIdx.x;
    int n0 = blockIdx.x * 64, c0 = blockIdx.y * 64, b = blockIdx.z;
    const float* xp = x + (size_t)b * C_ * N_;
    for (int it = 0; it < 16; it++) {
        int idx = it * 256 + tid;
        int c = idx >> 6, n = idx & 63;
        T[c][n] = xp[(size_t)(c0 + c) * N_ + n0 + n];
    }
    __syncthreads();
    u16* op = xT + (size_t)b * N_ * C_;
    for (int it = 0; it < 8; it++) {
        int idx = it * 256 + tid;
        int n = idx >> 5, c2 = (idx & 31) * 2;
        uint32_t lo = f2bf(T[c2][n]);
        uint32_t hi = f2bf(T[c2 + 1][n]);
        *(uint32_t*)&op[(size_t)(n0 + n) * C_ + c0 + c2] = lo | (hi << 16);
    }
}

// ---------------------------------------------------------------------------
// Kw: wq/wk/wv fp32 -> wb bf16 [3][512][256]
// ---------------------------------------------------------------------------
__global__ __launch_bounds__(256) void cvtw_kernel(const float* __restrict__ wq,
                                                   const float* __restrict__ wk,
                                                   const float* __restrict__ wv,
                                                   u16* __restrict__ wb) {
    int m = blockIdx.y;
    const float* s = m == 0 ? wq : (m == 1 ? wk : wv);
    int i = blockIdx.x * 256 + threadIdx.x;
    wb[(size_t)m * 131072 + i] = f2bf(s[i]);
}

// ---------------------------------------------------------------------------
// K1: fused QKV projection (MFMA) + bias + LN(dim) + per-kind epilogue.
//   kv=1: kinds {k,v}; k stores exp(LN(k)) bf16 and atomically accumulates
//         rowsum rs[b][512]. grid (128, 8, B)
//   kv=0: kind q (softmax over dim), writes qT[b][n][512]. grid (128, 4, B)
// ---------------------------------------------------------------------------
__global__ __launch_bounds__(256) void qkv_kernel(
    const u16* __restrict__ xT, const u16* __restrict__ wb,
    const float* __restrict__ bq, const float* __restrict__ bk, const float* __restrict__ bv,
    const float* __restrict__ gq, const float* __restrict__ beq,
    const float* __restrict__ gk, const float* __restrict__ bek,
    const float* __restrict__ gv, const float* __restrict__ bev,
    u16* __restrict__ qT, u16* __restrict__ eK, u16* __restrict__ vb,
    float* __restrict__ rs, int kv)
{
    __shared__ u16 WS[128 * LSQ];
    __shared__ u16 XS[128 * LSQ];
    int tid = threadIdx.x;
    int lane = tid & 63, wid = tid >> 6;
    int quad = lane >> 4, l15 = lane & 15;
    int wm = wid >> 1, wn = wid & 1;
    int sec = blockIdx.y;
    int kind, pair;
    if (kv) { kind = 1 + (sec >> 2); pair = sec & 3; }
    else    { kind = 0;              pair = sec; }
    int r0 = pair * 128;
    int n0 = blockIdx.x * 128;
    int b  = blockIdx.z;

    const float* bptr  = kind == 0 ? bq  : (kind == 1 ? bk  : bv);
    const float* gptr  = kind == 0 ? gq  : (kind == 1 ? gk  : gv);
    const float* beptr = kind == 0 ? beq : (kind == 1 ? bek : bev);

    const u16* wsrc = wb + (size_t)kind * 131072 + (size_t)r0 * 256;
    const u16* xsrc = xT + ((size_t)b * N_ + n0) * 256;

    f32x4 acc[4][4];
#pragma unroll
    for (int i = 0; i < 4; i++)
#pragma unroll
        for (int j = 0; j < 4; j++) acc[i][j] = (f32x4){0.f, 0.f, 0.f, 0.f};

    const u16* aB = (kind == 0) ? (WS + wm * 64 * LSQ) : (XS + wn * 64 * LSQ);
    const u16* bB = (kind == 0) ? (XS + wn * 64 * LSQ) : (WS + wm * 64 * LSQ);

    for (int kc = 0; kc < 4; kc++) {
#pragma unroll
        for (int it = 0; it < 4; it++) {
            int idx = it * 256 + tid;
            int row = idx >> 3, k8 = (idx & 7) * 8;
            *(s16x8*)&WS[row * LSQ + k8] = *(const s16x8*)&wsrc[(size_t)row * 256 + kc * 64 + k8];
            *(s16x8*)&XS[row * LSQ + k8] = *(const s16x8*)&xsrc[(size_t)row * 256 + kc * 64 + k8];
        }
        __syncthreads();
#pragma unroll
        for (int ks = 0; ks < 2; ks++) {
            int ko = ks * 32 + quad * 8;
            s16x8 af[4], bff[4];
#pragma unroll
            for (int f = 0; f < 4; f++) {
                af[f]  = *(const s16x8*)&aB[(f * 16 + l15) * LSQ + ko];
                bff[f] = *(const s16x8*)&bB[(f * 16 + l15) * LSQ + ko];
            }
#pragma unroll
            for (int i = 0; i < 4; i++)
#pragma unroll
                for (int j = 0; j < 4; j++)
                    acc[i][j] = __builtin_amdgcn_mfma_f32_16x16x32_bf16(af[i], bff[j], acc[i][j], 0, 0, 0);
        }
        __syncthreads();
    }

    if (kind == 0) {
        // q: value(mf,nf,reg): row rl = mf*16+quad*4+reg, col n = wn*64+nf*16+l15
        float bA[4][4], gA[4][4], eA[4][4];
#pragma unroll
        for (int mf = 0; mf < 4; mf++)
#pragma unroll
            for (int r = 0; r < 4; r++) {
                int rl = mf * 16 + quad * 4 + r;
                bA[mf][r] = bptr[r0 + wm * 64 + rl];
                gA[mf][r] = gptr[rl];
                eA[mf][r] = beptr[rl];
            }
#pragma unroll
        for (int mf = 0; mf < 4; mf++)
#pragma unroll
            for (int nf = 0; nf < 4; nf++)
#pragma unroll
                for (int r = 0; r < 4; r++) acc[mf][nf][r] += bA[mf][r];
#pragma unroll
        for (int nf = 0; nf < 4; nf++) {
            float s = 0.f, s2 = 0.f;
#pragma unroll
            for (int mf = 0; mf < 4; mf++)
#pragma unroll
                for (int r = 0; r < 4; r++) { float v = acc[mf][nf][r]; s += v; s2 += v * v; }
            s  += __shfl_xor(s, 16);  s  += __shfl_xor(s, 32);
            s2 += __shfl_xor(s2, 16); s2 += __shfl_xor(s2, 32);
            float mu = s * (1.f / 64.f);
            float rstd = rsqrtf(s2 * (1.f / 64.f) - mu * mu + 1e-5f);
#pragma unroll
            for (int mf = 0; mf < 4; mf++)
#pragma unroll
                for (int r = 0; r < 4; r++)
                    acc[mf][nf][r] = (acc[mf][nf][r] - mu) * rstd * gA[mf][r] + eA[mf][r];
        }
        const float s_q = 0.35355339059327373f;
#pragma unroll
        for (int nf = 0; nf < 4; nf++) {
            float m = -1e30f;
#pragma unroll
            for (int mf = 0; mf < 4; mf++)
#pragma unroll
                for (int r = 0; r < 4; r++) { acc[mf][nf][r] *= s_q; m = fmaxf(m, acc[mf][nf][r]); }
            m = fmaxf(m, __shfl_xor(m, 16)); m = fmaxf(m, __shfl_xor(m, 32));
            float d = 0.f;
#pragma unroll
            for (int mf = 0; mf < 4; mf++)
#pragma unroll
                for (int r = 0; r < 4; r++) { float e = __expf(acc[mf][nf][r] - m); acc[mf][nf][r] = e; d += e; }
            d += __shfl_xor(d, 16); d += __shfl_xor(d, 32);
            float inv = 1.f / d;
#pragma unroll
            for (int mf = 0; mf < 4; mf++)
#pragma unroll
                for (int r = 0; r < 4; r++) acc[mf][nf][r] *= inv;
        }
        u16* qp = qT + (size_t)b * N_ * 512;
#pragma unroll
        for (int mf = 0; mf < 4; mf++)
#pragma unroll
            for (int nf = 0; nf < 4; nf++) {
                int n = n0 + wn * 64 + nf * 16 + l15;
                int g0 = r0 + wm * 64 + mf * 16 + quad * 4;
                uint64_t w0 = (uint64_t)f2bf(acc[mf][nf][0]) | ((uint64_t)f2bf(acc[mf][nf][1]) << 16) |
                              ((uint64_t)f2bf(acc[mf][nf][2]) << 32) | ((uint64_t)f2bf(acc[mf][nf][3]) << 48);
                *(uint64_t*)&qp[(size_t)n * 512 + g0] = w0;
            }
    } else {
        // k/v: value(mf,nf,reg): n = wn*64+mf*16+quad*4+reg, row rl = nf*16+l15
        float bB_[4], gB[4], eB[4];
#pragma unroll
        for (int nf = 0; nf < 4; nf++) {
            int rl = nf * 16 + l15;
            bB_[nf] = bptr[r0 + wm * 64 + rl];
            gB[nf]  = gptr[rl];
            eB[nf]  = beptr[rl];
        }
#pragma unroll
        for (int mf = 0; mf < 4; mf++)
#pragma unroll
            for (int nf = 0; nf < 4; nf++)
#pragma unroll
                for (int r = 0; r < 4; r++) acc[mf][nf][r] += bB_[nf];
        float sa[4][4], sb[4][4];
#pragma unroll
        for (int mf = 0; mf < 4; mf++)
#pragma unroll
            for (int r = 0; r < 4; r++) {
                float s = 0.f, s2 = 0.f;
#pragma unroll
                for (int nf = 0; nf < 4; nf++) { float v = acc[mf][nf][r]; s += v; s2 += v * v; }
                sa[mf][r] = s; sb[mf][r] = s2;
            }
#pragma unroll
        for (int msk = 1; msk <= 8; msk <<= 1)
#pragma unroll
            for (int mf = 0; mf < 4; mf++)
#pragma unroll
                for (int r = 0; r < 4; r++) {
                    sa[mf][r] += __shfl_xor(sa[mf][r], msk);
                    sb[mf][r] += __shfl_xor(sb[mf][r], msk);
                }
#pragma unroll
        for (int mf = 0; mf < 4; mf++)
#pragma unroll
            for (int r = 0; r < 4; r++) {
                float mu = sa[mf][r] * (1.f / 64.f);
                float rstd = rsqrtf(sb[mf][r] * (1.f / 64.f) - mu * mu + 1e-5f);
#pragma unroll
                for (int nf = 0; nf < 4; nf++)
                    acc[mf][nf][r] = (acc[mf][nf][r] - mu) * rstd * gB[nf] + eB[nf];
            }
        if (kind == 1) {
            // exp + rowsum accumulate
#pragma unroll
            for (int mf = 0; mf < 4; mf++)
#pragma unroll
                for (int nf = 0; nf < 4; nf++)
#pragma unroll
                    for (int r = 0; r < 4; r++) acc[mf][nf][r] = __expf(acc[mf][nf][r]);
#pragma unroll
            for (int nf = 0; nf < 4; nf++) {
                float s = 0.f;
#pragma unroll
                for (int mf = 0; mf < 4; mf++)
#pragma unroll
                    for (int r = 0; r < 4; r++) s += acc[mf][nf][r];
                s += __shfl_xor(s, 16); s += __shfl_xor(s, 32);
                if (quad == 0)
                    atomicAdd(&rs[(size_t)b * 512 + r0 + wm * 64 + nf * 16 + l15], s);
            }
        }
        u16* op = (kind == 1) ? eK : vb;
#pragma unroll
        for (int mf = 0; mf < 4; mf++)
#pragma unroll
            for (int nf = 0; nf < 4; nf++) {
                int n = n0 + wn * 64 + mf * 16 + quad * 4;
                int gr = r0 + wm * 64 + nf * 16 + l15;
                uint64_t w0 = (uint64_t)f2bf(acc[mf][nf][0]) | ((uint64_t)f2bf(acc[mf][nf][1]) << 16) |
                              ((uint64_t)f2bf(acc[mf][nf][2]) << 32) | ((uint64_t)f2bf(acc[mf][nf][3]) << 48);
                *(uint64_t*)&op[((size_t)b * 512 + gr) * N_ + n] = w0;
            }
    }
}

// ---------------------------------------------------------------------------
// K2: ctx[b,h,kd,vd] += sum_n eK[kd,n]*v[vd,n]  — pure bf16 GEMM, K=1024/block
// grid (16 ns, 8 h, 4 b), block 256. Global fp32 atomicAdd after LDS reduce.
// ---------------------------------------------------------------------------
__global__ __launch_bounds__(256) void ctx_kernel(
    const u16* __restrict__ eK, const u16* __restrict__ vb,
    float* __restrict__ ctx_acc)
{
    __shared__ u16 ES[64 * LS2];
    __shared__ u16 VS[64 * LS2];
    __shared__ float CTXS[64 * 66];
    int tid = threadIdx.x;
    int lane = tid & 63, wid = tid >> 6;
    int quad = lane >> 4, l15 = lane & 15;
    int ns = blockIdx.x, h = blockIdx.y, b = blockIdx.z;
    for (int i = tid; i < 64 * 66; i += 256) CTXS[i] = 0.f;
    const u16* kp = eK + ((size_t)b * 512 + h * 64) * N_;
    const u16* vp = vb + ((size_t)b * 512 + h * 64) * N_;
    f32x4 acc[4][4];
#pragma unroll
    for (int i = 0; i < 4; i++)
#pragma unroll
        for (int j = 0; j < 4; j++) acc[i][j] = (f32x4){0.f, 0.f, 0.f, 0.f};

    for (int ch = 0; ch < 8; ch++) {
        int nc = ns * 1024 + ch * 128;
#pragma unroll
        for (int it = 0; it < 4; it++) {
            int idx = it * 256 + tid;
            int row = idx >> 4, g8 = (idx & 15) * 8;
            *(s16x8*)&ES[row * LS2 + g8] = *(const s16x8*)&kp[(size_t)row * N_ + nc + g8];
            *(s16x8*)&VS[row * LS2 + g8] = *(const s16x8*)&vp[(size_t)row * N_ + nc + g8];
        }
        __syncthreads();
        int ko = wid * 32 + quad * 8;
        s16x8 af[4], bvf[4];
#pragma unroll
        for (int f = 0; f < 4; f++) {
            af[f]  = *(const s16x8*)&ES[(f * 16 + l15) * LS2 + ko];
            bvf[f] = *(const s16x8*)&VS[(f * 16 + l15) * LS2 + ko];
        }
#pragma unroll
        for (int i = 0; i < 4; i++)
#pragma unroll
            for (int j = 0; j < 4; j++)
                acc[i][j] = __builtin_amdgcn_mfma_f32_16x16x32_bf16(af[i], bvf[j], acc[i][j], 0, 0, 0);
        __syncthreads();
    }
#pragma unroll
    for (int mf = 0; mf < 4; mf++)
#pragma unroll
        for (int nf = 0; nf < 4; nf++)
#pragma unroll
            for (int r = 0; r < 4; r++) {
                int kd = mf * 16 + quad * 4 + r, vd = nf * 16 + l15;
                atomicAdd(&CTXS[kd * 66 + vd], acc[mf][nf][r]);
            }
    __syncthreads();
    size_t base = ((size_t)b * 8 + h) * 4096;
    for (int i = tid; i < 4096; i += 256)
        atomicAdd(&ctx_acc[base + i], CTXS[(i >> 6) * 66 + (i & 63)]);
}

// ---------------------------------------------------------------------------
// K3: Weff[b][c][h*64+kd] = sum_vd wo[c][h*64+vd] * (ctx[b,h,kd,vd]/rs[b,h*64+kd])
// grid (8 h, 4 b, 4 kd-chunks), block 256 (thread = c).
// ---------------------------------------------------------------------------
__global__ __launch_bounds__(256) void weff_kernel(
    const float* __restrict__ ctx_acc, const float* __restrict__ rs,
    const float* __restrict__ wo, u16* __restrict__ Weffb)
{
    __shared__ float CT[16][65];
    int tid = threadIdx.x;
    int h = blockIdx.x, b = blockIdx.y, kc = blockIdx.z;
    for (int i = tid; i < 1024; i += 256) {
        int kdl = i >> 6, vd = i & 63;
        int kd = kc * 16 + kdl;
        CT[kdl][vd] = ctx_acc[(((size_t)b * 8 + h) * 64 + kd) * 64 + vd] /
                      rs[(size_t)b * 512 + h * 64 + kd];
    }
    __syncthreads();
    int c = tid;
    float wrow[64];
    const float4* wp = (const float4*)(wo + (size_t)c * 512 + h * 64);
#pragma unroll
    for (int i = 0; i < 16; i++) { float4 t = wp[i]; wrow[i*4] = t.x; wrow[i*4+1] = t.y; wrow[i*4+2] = t.z; wrow[i*4+3] = t.w; }
    for (int kdl = 0; kdl < 16; kdl++) {
        float s = 0.f;
#pragma unroll
        for (int vd = 0; vd < 64; vd++) s += wrow[vd] * CT[kdl][vd];
        Weffb[((size_t)b * 256 + c) * 512 + h * 64 + kc * 16 + kdl] = f2bf(s);
    }
}

// ---------------------------------------------------------------------------
// K4: out[c][n] = sum_r Weff[c][r] qT[n][r] + bo[c]   (MFMA, K=512)
// ---------------------------------------------------------------------------
__global__ __launch_bounds__(256) void out_kernel(
    const u16* __restrict__ Weffb, const u16* __restrict__ qT,
    const float* __restrict__ bo, float* __restrict__ out)
{
    __shared__ u16 WS[128 * LSQ];
    __shared__ u16 XS[128 * LSQ];
    int tid = threadIdx.x;
    int lane = tid & 63, wid = tid >> 6;
    int quad = lane >> 4, l15 = lane & 15;
    int wm = wid >> 1, wn = wid & 1;
    int n0 = blockIdx.x * 128, c0 = blockIdx.y * 128, b = blockIdx.z;
    const u16* asrc = Weffb + ((size_t)b * 256 + c0) * 512;
    const u16* bsrc = qT + ((size_t)b * N_ + n0) * 512;

    f32x4 acc[4][4];
#pragma unroll
    for (int i = 0; i < 4; i++)
#pragma unroll
        for (int j = 0; j < 4; j++) acc[i][j] = (f32x4){0.f, 0.f, 0.f, 0.f};

    for (int kc = 0; kc < 8; kc++) {
#pragma unroll
        for (int it = 0; it < 4; it++) {
            int idx = it * 256 + tid;
            int row = idx >> 3, k8 = (idx & 7) * 8;
            *(s16x8*)&WS[row * LSQ + k8] = *(const s16x8*)&asrc[(size_t)row * 512 + kc * 64 + k8];
            *(s16x8*)&XS[row * LSQ + k8] = *(const s16x8*)&bsrc[(size_t)row * 512 + kc * 64 + k8];
        }
        __syncthreads();
#pragma unroll
        for (int ks = 0; ks < 2; ks++) {
            int ko = ks * 32 + quad * 8;
            s16x8 af[4], bqf[4];
#pragma unroll
            for (int f = 0; f < 4; f++) {
                af[f]  = *(const s16x8*)&WS[(wm * 64 + f * 16 + l15) * LSQ + ko];
                bqf[f] = *(const s16x8*)&XS[(wn * 64 + f * 16 + l15) * LSQ + ko];
            }
#pragma unroll
            for (int i = 0; i < 4; i++)
#pragma unroll
                for (int j = 0; j < 4; j++)
                    acc[i][j] = __builtin_amdgcn_mfma_f32_16x16x32_bf16(af[i], bqf[j], acc[i][j], 0, 0, 0);
        }
        __syncthreads();
    }
#pragma unroll
    for (int mf = 0; mf < 4; mf++)
#pragma unroll
        for (int r = 0; r < 4; r++) {
            int c = c0 + wm * 64 + mf * 16 + quad * 4 + r;
            float bov = bo[c];
#pragma unroll
            for (int nf = 0; nf < 4; nf++)
                out[((size_t)b * 256 + c) * N_ + n0 + wn * 64 + nf * 16 + l15] = acc[mf][nf][r] + bov;
        }
}

extern "C" void kernel_launch(void* const* d_in, const int* in_sizes, int n_in,
                              void* d_out, int out_size, void* d_ws, size_t ws_size,
                              hipStream_t stream) {
    const float* x   = (const float*)d_in[0];
    const float* wq  = (const float*)d_in[1];
    const float* bq  = (const float*)d_in[2];
    const float* wk  = (const float*)d_in[3];
    const float* bk  = (const float*)d_in[4];
    const float* wv  = (const float*)d_in[5];
    const float* bv  = (const float*)d_in[6];
    const float* wo  = (const float*)d_in[7];
    const float* bo  = (const float*)d_in[8];
    const float* gq  = (const float*)d_in[9];
    const float* beq = (const float*)d_in[10];
    const float* gk  = (const float*)d_in[11];
    const float* bek = (const float*)d_in[12];
    const float* gv  = (const float*)d_in[13];
    const float* bev = (const float*)d_in[14];
    float* out = (float*)d_out;

    char* ws = (char*)d_ws;
    // xT  [0, 33554432)                    bf16 [B][N][C]
    // wb  [33554432, 34340864)             bf16 [3][512][256]
    // eK  [34340864, 101449728)            bf16 [B][512][N]   (dead after ctx)
    // qT  [34340864, 101449728)            bf16 [B][N][512]   (aliases eK; written after ctx)
    // vb  [101449728, 168558592)           bf16 [B][512][N]
    // ctx [168558592, 169082880)           fp32 [B][8][64][64]
    // rs  [169082880, 169091072)           fp32 [B][512]
    // Weff[169091072, 170139648)           bf16 [B][256][512]
    u16* xT      = (u16*)(ws);
    u16* wb      = (u16*)(ws + 33554432ULL);
    u16* eK      = (u16*)(ws + 34340864ULL);
    u16* qT      = (u16*)(ws + 34340864ULL);
    u16* vbuf    = (u16*)(ws + 101449728ULL);
    float* ctx_a = (float*)(ws + 168558592ULL);
    float* rs    = (float*)(ws + 169082880ULL);
    u16* Weffb   = (u16*)(ws + 169091072ULL);

    cvtw_kernel<<<dim3(512, 3), 256, 0, stream>>>(wq, wk, wv, wb);
    transpose_kernel<<<dim3(256, 4, 4), 256, 0, stream>>>(x, xT);
    zero_kernel<<<dim3(520), 256, 0, stream>>>(ctx_a, 133120);  // ctx_acc + rs (contiguous)

    // k,v for all batches (kind 1,2), with exp(k) + rowsum fused
    qkv_kernel<<<dim3(128, 8, 4), 256, 0, stream>>>(
        xT, wb, bq, bk, bv, gq, beq, gk, bek, gv, bev, qT, eK, vbuf, rs, 1);

    ctx_kernel<<<dim3(16, 8, 4), 256, 0, stream>>>(eK, vbuf, ctx_a);

    // q for all batches (kind 0) — qT aliases the now-dead eK region
    qkv_kernel<<<dim3(128, 4, 4), 256, 0, stream>>>(
        xT, wb, bq, bk, bv, gq, beq, gk, bek, gv, bev, qT, eK, vbuf, rs, 0);

    weff_kernel<<<dim3(8, 4, 4), 256, 0, stream>>>(ctx_a, rs, wo, Weffb);

    out_kernel<<<dim3(128, 2, 4), 256, 0, stream>>>(Weffb, qT, bo, out);
}

// Round 4
// 382.084 us; speedup vs baseline: 3.4331x; 1.2561x over previous
//
#include <hip/hip_runtime.h>
#include <hip/hip_bf16.h>
#include <stdint.h>

typedef unsigned short u16;
typedef __attribute__((__vector_size__(16))) short s16x8;
typedef __attribute__((__vector_size__(16))) float f32x4;

#define N_ 16384
#define C_ 256

__device__ __forceinline__ float bf2f(u16 u) {
    union { uint32_t i; float f; } v; v.i = ((uint32_t)u) << 16; return v.f;
}
__device__ __forceinline__ u16 f2bf(float f) {
    union { uint32_t i; float f; } v; v.f = f;
    uint32_t u = v.i;
    return (u16)((u + 0x7FFFu + ((u >> 16) & 1u)) >> 16);
}

// async global->LDS, 16 B per lane. LDS dest = wave-uniform base + lane*16.
__device__ __forceinline__ void gl_lds16(const u16* g, u16* l) {
    __builtin_amdgcn_global_load_lds((__attribute__((address_space(1))) void*)g,
                                     (__attribute__((address_space(3))) void*)l,
                                     16, 0, 0);
}

__global__ __launch_bounds__(256) void zero_kernel(float* __restrict__ p, int n) {
    int i = blockIdx.x * 256 + threadIdx.x;
    if (i < n) p[i] = 0.f;
}

// ---------------------------------------------------------------------------
// K0: x fp32 [B][C][N] -> xT bf16 [B][N][C]
// ---------------------------------------------------------------------------
__global__ __launch_bounds__(256) void transpose_kernel(const float* __restrict__ x,
                                                        u16* __restrict__ xT) {
    __shared__ float T[64][65];
    int tid = threadIdx.x;
    int n0 = blockIdx.x * 64, c0 = blockIdx.y * 64, b = blockIdx.z;
    const float* xp = x + (size_t)b * C_ * N_;
    for (int it = 0; it < 16; it++) {
        int idx = it * 256 + tid;
        int c = idx >> 6, n = idx & 63;
        T[c][n] = xp[(size_t)(c0 + c) * N_ + n0 + n];
    }
    __syncthreads();
    u16* op = xT + (size_t)b * N_ * C_;
    for (int it = 0; it < 8; it++) {
        int idx = it * 256 + tid;
        int n = idx >> 5, c2 = (idx & 31) * 2;
        uint32_t lo = f2bf(T[c2][n]);
        uint32_t hi = f2bf(T[c2 + 1][n]);
        *(uint32_t*)&op[(size_t)(n0 + n) * C_ + c0 + c2] = lo | (hi << 16);
    }
}

// ---------------------------------------------------------------------------
// Kw: wq/wk/wv fp32 -> wb bf16 [3][512][256]
// ---------------------------------------------------------------------------
__global__ __launch_bounds__(256) void cvtw_kernel(const float* __restrict__ wq,
                                                   const float* __restrict__ wk,
                                                   const float* __restrict__ wv,
                                                   u16* __restrict__ wb) {
    int m = blockIdx.y;
    const float* s = m == 0 ? wq : (m == 1 ? wk : wv);
    int i = blockIdx.x * 256 + threadIdx.x;
    wb[(size_t)m * 131072 + i] = f2bf(s[i]);
}

// ===========================================================================
// Swizzled Tile A: [128 rows][64 halves], slot(row,c) = row*64 + ((c^(row&7))*8)
// staged via global_load_lds: lane l of issue i (wave w): row=(w*4+i)*8+l/8,
// loads global chunk c = (l&7)^(l>>3) -> lands at its swizzled slot.
// Fragment read (row, cc): LDS half-offset row*64 + ((cc^(row&7))*8) -> 2-way banks.
// ===========================================================================

// ---------------------------------------------------------------------------
// K1a: k,v projection + bias + LN + (k: exp + rowsum) -> blocked swizzled
//      tiles eKb/vbb [b][h][128 tiles][64][128] (pre-swizzled for ctx).
// grid (128 ntiles, 8 sec = kind(2)x pair(4), B); block 256 (2x2 waves).
// ---------------------------------------------------------------------------
__global__ __launch_bounds__(256) void kv_kernel(
    const u16* __restrict__ xT, const u16* __restrict__ wb,
    const float* __restrict__ bk, const float* __restrict__ bv,
    const float* __restrict__ gk, const float* __restrict__ bek,
    const float* __restrict__ gv, const float* __restrict__ bev,
    u16* __restrict__ eKb, u16* __restrict__ vbb, float* __restrict__ rs)
{
    __shared__ u16 WS[128 * 64];
    __shared__ u16 XS[128 * 64];
    int tid = threadIdx.x;
    int lane = tid & 63, wid = tid >> 6;
    int quad = lane >> 4, l15 = lane & 15;
    int wm = wid >> 1, wn = wid & 1;
    int bx = blockIdx.x, sec = blockIdx.y, b = blockIdx.z;
    int kind2 = sec >> 2, pair = sec & 3;      // kind2: 0=k, 1=v
    int r0 = pair * 128;
    int n0 = bx * 128;

    const float* bptr  = kind2 ? bv  : bk;
    const float* gptr  = kind2 ? gv  : gk;
    const float* beptr = kind2 ? bev : bek;
    const u16* wsrc = wb + (size_t)(1 + kind2) * 131072 + (size_t)r0 * 256;
    const u16* xsrc = xT + ((size_t)b * N_ + n0) * 256;

    f32x4 acc[4][4];
#pragma unroll
    for (int i = 0; i < 4; i++)
#pragma unroll
        for (int j = 0; j < 4; j++) acc[i][j] = (f32x4){0.f, 0.f, 0.f, 0.f};

    int srow = lane >> 3;
    int sc8  = ((lane & 7) ^ srow) * 8;

    for (int kc = 0; kc < 4; kc++) {
        int koff = kc * 64 + sc8;
#pragma unroll
        for (int i = 0; i < 4; i++) {
            int row = (wid * 4 + i) * 8 + srow;
            gl_lds16(&wsrc[(size_t)row * 256 + koff], &WS[(wid * 4 + i) * 512]);
            gl_lds16(&xsrc[(size_t)row * 256 + koff], &XS[(wid * 4 + i) * 512]);
        }
        __syncthreads();
#pragma unroll
        for (int ks = 0; ks < 2; ks++) {
            int cc = ks * 4 + quad;
            s16x8 af[4], bf[4];
#pragma unroll
            for (int f = 0; f < 4; f++) {
                int ar = wn * 64 + f * 16 + l15;   // A = x/n side
                int br = wm * 64 + f * 16 + l15;   // B = weight side
                af[f] = *(const s16x8*)&XS[ar * 64 + ((cc ^ (ar & 7)) * 8)];
                bf[f] = *(const s16x8*)&WS[br * 64 + ((cc ^ (br & 7)) * 8)];
            }
#pragma unroll
            for (int i = 0; i < 4; i++)
#pragma unroll
                for (int j = 0; j < 4; j++)
                    acc[i][j] = __builtin_amdgcn_mfma_f32_16x16x32_bf16(af[i], bf[j], acc[i][j], 0, 0, 0);
        }
        __syncthreads();
    }

    // value(mf,nf,reg): n_local = wn*64+mf*16+quad*4+reg, head-row rh = nf*16+l15
    int head = pair * 2 + wm;
    float bB_[4], gB[4], eB[4];
#pragma unroll
    for (int nf = 0; nf < 4; nf++) {
        int rl = nf * 16 + l15;
        bB_[nf] = bptr[head * 64 + rl];
        gB[nf]  = gptr[rl];
        eB[nf]  = beptr[rl];
    }
#pragma unroll
    for (int mf = 0; mf < 4; mf++)
#pragma unroll
        for (int nf = 0; nf < 4; nf++)
#pragma unroll
            for (int r = 0; r < 4; r++) acc[mf][nf][r] += bB_[nf];
    float sa[4][4], sb[4][4];
#pragma unroll
    for (int mf = 0; mf < 4; mf++)
#pragma unroll
        for (int r = 0; r < 4; r++) {
            float s = 0.f, s2 = 0.f;
#pragma unroll
            for (int nf = 0; nf < 4; nf++) { float v = acc[mf][nf][r]; s += v; s2 += v * v; }
            sa[mf][r] = s; sb[mf][r] = s2;
        }
#pragma unroll
    for (int msk = 1; msk <= 8; msk <<= 1)
#pragma unroll
        for (int mf = 0; mf < 4; mf++)
#pragma unroll
            for (int r = 0; r < 4; r++) {
                sa[mf][r] += __shfl_xor(sa[mf][r], msk);
                sb[mf][r] += __shfl_xor(sb[mf][r], msk);
            }
#pragma unroll
    for (int mf = 0; mf < 4; mf++)
#pragma unroll
        for (int r = 0; r < 4; r++) {
            float mu = sa[mf][r] * (1.f / 64.f);
            float rstd = rsqrtf(sb[mf][r] * (1.f / 64.f) - mu * mu + 1e-5f);
#pragma unroll
            for (int nf = 0; nf < 4; nf++)
                acc[mf][nf][r] = (acc[mf][nf][r] - mu) * rstd * gB[nf] + eB[nf];
        }
    if (kind2 == 0) {
#pragma unroll
        for (int mf = 0; mf < 4; mf++)
#pragma unroll
            for (int nf = 0; nf < 4; nf++)
#pragma unroll
                for (int r = 0; r < 4; r++) acc[mf][nf][r] = __expf(acc[mf][nf][r]);
#pragma unroll
        for (int nf = 0; nf < 4; nf++) {
            float s = 0.f;
#pragma unroll
            for (int mf = 0; mf < 4; mf++)
#pragma unroll
                for (int r = 0; r < 4; r++) s += acc[mf][nf][r];
            s += __shfl_xor(s, 16); s += __shfl_xor(s, 32);
            if (quad == 0)
                atomicAdd(&rs[(size_t)b * 512 + head * 64 + nf * 16 + l15], s);
        }
    }
    // store to blocked swizzled tile [b][head][tile bx][64][128]
    u16* op = (kind2 == 0) ? eKb : vbb;
    size_t tb = ((size_t)((b * 8 + head) * 128 + bx)) * 8192;
#pragma unroll
    for (int mf = 0; mf < 4; mf++)
#pragma unroll
        for (int nf = 0; nf < 4; nf++) {
            int rh = nf * 16 + l15;
            int ln = wn * 64 + mf * 16 + quad * 4;
            int c  = ln >> 3;
            int off = rh * 128 + ((c ^ (rh & 15)) * 8) + (ln & 7);
            uint64_t w0 = (uint64_t)f2bf(acc[mf][nf][0]) | ((uint64_t)f2bf(acc[mf][nf][1]) << 16) |
                          ((uint64_t)f2bf(acc[mf][nf][2]) << 32) | ((uint64_t)f2bf(acc[mf][nf][3]) << 48);
            *(uint64_t*)&op[tb + off] = w0;
        }
}

// ---------------------------------------------------------------------------
// K1b: q projection + bias + LN + softmax(dim) -> qT[b][n][512]
// grid (128 ntiles, 4 pairs, B); block 256.
// ---------------------------------------------------------------------------
__global__ __launch_bounds__(256) void q_kernel(
    const u16* __restrict__ xT, const u16* __restrict__ wb,
    const float* __restrict__ bq, const float* __restrict__ gq, const float* __restrict__ beq,
    u16* __restrict__ qT)
{
    __shared__ u16 WS[128 * 64];
    __shared__ u16 XS[128 * 64];
    int tid = threadIdx.x;
    int lane = tid & 63, wid = tid >> 6;
    int quad = lane >> 4, l15 = lane & 15;
    int wm = wid >> 1, wn = wid & 1;
    int bx = blockIdx.x, pair = blockIdx.y, b = blockIdx.z;
    int r0 = pair * 128;
    int n0 = bx * 128;

    const u16* wsrc = wb + (size_t)r0 * 256;
    const u16* xsrc = xT + ((size_t)b * N_ + n0) * 256;

    f32x4 acc[4][4];
#pragma unroll
    for (int i = 0; i < 4; i++)
#pragma unroll
        for (int j = 0; j < 4; j++) acc[i][j] = (f32x4){0.f, 0.f, 0.f, 0.f};

    int srow = lane >> 3;
    int sc8  = ((lane & 7) ^ srow) * 8;

    for (int kc = 0; kc < 4; kc++) {
        int koff = kc * 64 + sc8;
#pragma unroll
        for (int i = 0; i < 4; i++) {
            int row = (wid * 4 + i) * 8 + srow;
            gl_lds16(&wsrc[(size_t)row * 256 + koff], &WS[(wid * 4 + i) * 512]);
            gl_lds16(&xsrc[(size_t)row * 256 + koff], &XS[(wid * 4 + i) * 512]);
        }
        __syncthreads();
#pragma unroll
        for (int ks = 0; ks < 2; ks++) {
            int cc = ks * 4 + quad;
            s16x8 af[4], bf[4];
#pragma unroll
            for (int f = 0; f < 4; f++) {
                int ar = wm * 64 + f * 16 + l15;   // A = weight side
                int br = wn * 64 + f * 16 + l15;   // B = x/n side
                af[f] = *(const s16x8*)&WS[ar * 64 + ((cc ^ (ar & 7)) * 8)];
                bf[f] = *(const s16x8*)&XS[br * 64 + ((cc ^ (br & 7)) * 8)];
            }
#pragma unroll
            for (int i = 0; i < 4; i++)
#pragma unroll
                for (int j = 0; j < 4; j++)
                    acc[i][j] = __builtin_amdgcn_mfma_f32_16x16x32_bf16(af[i], bf[j], acc[i][j], 0, 0, 0);
        }
        __syncthreads();
    }

    // value(mf,nf,reg): row rl = mf*16+quad*4+reg (in head), col n = wn*64+nf*16+l15
    float bA[4][4], gA[4][4], eA[4][4];
#pragma unroll
    for (int mf = 0; mf < 4; mf++)
#pragma unroll
        for (int r = 0; r < 4; r++) {
            int rl = mf * 16 + quad * 4 + r;
            bA[mf][r] = bq[r0 + wm * 64 + rl];
            gA[mf][r] = gq[rl];
            eA[mf][r] = beq[rl];
        }
#pragma unroll
    for (int mf = 0; mf < 4; mf++)
#pragma unroll
        for (int nf = 0; nf < 4; nf++)
#pragma unroll
            for (int r = 0; r < 4; r++) acc[mf][nf][r] += bA[mf][r];
#pragma unroll
    for (int nf = 0; nf < 4; nf++) {
        float s = 0.f, s2 = 0.f;
#pragma unroll
        for (int mf = 0; mf < 4; mf++)
#pragma unroll
            for (int r = 0; r < 4; r++) { float v = acc[mf][nf][r]; s += v; s2 += v * v; }
        s  += __shfl_xor(s, 16);  s  += __shfl_xor(s, 32);
        s2 += __shfl_xor(s2, 16); s2 += __shfl_xor(s2, 32);
        float mu = s * (1.f / 64.f);
        float rstd = rsqrtf(s2 * (1.f / 64.f) - mu * mu + 1e-5f);
#pragma unroll
        for (int mf = 0; mf < 4; mf++)
#pragma unroll
            for (int r = 0; r < 4; r++)
                acc[mf][nf][r] = (acc[mf][nf][r] - mu) * rstd * gA[mf][r] + eA[mf][r];
    }
    const float s_q = 0.35355339059327373f;
#pragma unroll
    for (int nf = 0; nf < 4; nf++) {
        float m = -1e30f;
#pragma unroll
        for (int mf = 0; mf < 4; mf++)
#pragma unroll
            for (int r = 0; r < 4; r++) { acc[mf][nf][r] *= s_q; m = fmaxf(m, acc[mf][nf][r]); }
        m = fmaxf(m, __shfl_xor(m, 16)); m = fmaxf(m, __shfl_xor(m, 32));
        float d = 0.f;
#pragma unroll
        for (int mf = 0; mf < 4; mf++)
#pragma unroll
            for (int r = 0; r < 4; r++) { float e = __expf(acc[mf][nf][r] - m); acc[mf][nf][r] = e; d += e; }
        d += __shfl_xor(d, 16); d += __shfl_xor(d, 32);
        float inv = 1.f / d;
#pragma unroll
        for (int mf = 0; mf < 4; mf++)
#pragma unroll
            for (int r = 0; r < 4; r++) acc[mf][nf][r] *= inv;
    }
    u16* qp = qT + (size_t)b * N_ * 512;
#pragma unroll
    for (int mf = 0; mf < 4; mf++)
#pragma unroll
        for (int nf = 0; nf < 4; nf++) {
            int n = n0 + wn * 64 + nf * 16 + l15;
            int g0 = r0 + wm * 64 + mf * 16 + quad * 4;
            uint64_t w0 = (uint64_t)f2bf(acc[mf][nf][0]) | ((uint64_t)f2bf(acc[mf][nf][1]) << 16) |
                          ((uint64_t)f2bf(acc[mf][nf][2]) << 32) | ((uint64_t)f2bf(acc[mf][nf][3]) << 48);
            *(uint64_t*)&qp[(size_t)n * 512 + g0] = w0;
        }
}

// ---------------------------------------------------------------------------
// K2: ctx[b,h,kd,vd] += sum_n eK[kd,n]*v[vd,n] — identity-staged from blocked
// swizzled tiles. grid (16 ns, 8 h, 4 b), block 256, waves split K(n).
// ---------------------------------------------------------------------------
__global__ __launch_bounds__(256) void ctx_kernel(
    const u16* __restrict__ eKb, const u16* __restrict__ vbb,
    float* __restrict__ ctx_acc)
{
    __shared__ u16 ES[64 * 128];
    __shared__ u16 VS[64 * 128];
    __shared__ float CTXS[64 * 66];
    int tid = threadIdx.x;
    int lane = tid & 63, wid = tid >> 6;
    int quad = lane >> 4, l15 = lane & 15;
    int ns = blockIdx.x, h = blockIdx.y, b = blockIdx.z;
    for (int i = tid; i < 64 * 66; i += 256) CTXS[i] = 0.f;
    size_t hb = (size_t)(b * 8 + h) * 128;
    f32x4 acc[4][4];
#pragma unroll
    for (int i = 0; i < 4; i++)
#pragma unroll
        for (int j = 0; j < 4; j++) acc[i][j] = (f32x4){0.f, 0.f, 0.f, 0.f};

    for (int t = 0; t < 8; t++) {
        size_t tb = (hb + ns * 8 + t) * 8192;
#pragma unroll
        for (int i = 0; i < 4; i++) {
            size_t g = tb + ((size_t)((wid * 4 + i) * 64) + lane) * 8;
            gl_lds16(&eKb[g], &ES[(wid * 4 + i) * 512]);
            gl_lds16(&vbb[g], &VS[(wid * 4 + i) * 512]);
        }
        __syncthreads();
        int cc = wid * 4 + quad;
        s16x8 af[4], bf[4];
#pragma unroll
        for (int f = 0; f < 4; f++) {
            int off = (f * 16 + l15) * 128 + ((cc ^ l15) * 8);
            af[f] = *(const s16x8*)&ES[off];
            bf[f] = *(const s16x8*)&VS[off];
        }
#pragma unroll
        for (int i = 0; i < 4; i++)
#pragma unroll
            for (int j = 0; j < 4; j++)
                acc[i][j] = __builtin_amdgcn_mfma_f32_16x16x32_bf16(af[i], bf[j], acc[i][j], 0, 0, 0);
        __syncthreads();
    }
#pragma unroll
    for (int mf = 0; mf < 4; mf++)
#pragma unroll
        for (int nf = 0; nf < 4; nf++)
#pragma unroll
            for (int r = 0; r < 4; r++) {
                int kd = mf * 16 + quad * 4 + r, vd = nf * 16 + l15;
                atomicAdd(&CTXS[kd * 66 + vd], acc[mf][nf][r]);
            }
    __syncthreads();
    size_t base = ((size_t)b * 8 + h) * 4096;
    for (int i = tid; i < 4096; i += 256)
        atomicAdd(&ctx_acc[base + i], CTXS[(i >> 6) * 66 + (i & 63)]);
}

// ---------------------------------------------------------------------------
// K3: Weff[b][c][h*64+kd] = sum_vd wo[c][h*64+vd] * (ctx/rs)
// ---------------------------------------------------------------------------
__global__ __launch_bounds__(256) void weff_kernel(
    const float* __restrict__ ctx_acc, const float* __restrict__ rs,
    const float* __restrict__ wo, u16* __restrict__ Weffb)
{
    __shared__ float CT[16][65];
    int tid = threadIdx.x;
    int h = blockIdx.x, b = blockIdx.y, kc = blockIdx.z;
    for (int i = tid; i < 1024; i += 256) {
        int kdl = i >> 6, vd = i & 63;
        int kd = kc * 16 + kdl;
        CT[kdl][vd] = ctx_acc[(((size_t)b * 8 + h) * 64 + kd) * 64 + vd] /
                      rs[(size_t)b * 512 + h * 64 + kd];
    }
    __syncthreads();
    int c = tid;
    float wrow[64];
    const float4* wp = (const float4*)(wo + (size_t)c * 512 + h * 64);
#pragma unroll
    for (int i = 0; i < 16; i++) { float4 t = wp[i]; wrow[i*4] = t.x; wrow[i*4+1] = t.y; wrow[i*4+2] = t.z; wrow[i*4+3] = t.w; }
    for (int kdl = 0; kdl < 16; kdl++) {
        float s = 0.f;
#pragma unroll
        for (int vd = 0; vd < 64; vd++) s += wrow[vd] * CT[kdl][vd];
        Weffb[((size_t)b * 256 + c) * 512 + h * 64 + kc * 16 + kdl] = f2bf(s);
    }
}

// ---------------------------------------------------------------------------
// K4: out[c][n] = sum_r Weff[c][r] qT[n][r] + bo[c]   (MFMA, K=512)
// ---------------------------------------------------------------------------
__global__ __launch_bounds__(256) void out_kernel(
    const u16* __restrict__ Weffb, const u16* __restrict__ qT,
    const float* __restrict__ bo, float* __restrict__ out)
{
    __shared__ u16 WS[128 * 64];
    __shared__ u16 XS[128 * 64];
    int tid = threadIdx.x;
    int lane = tid & 63, wid = tid >> 6;
    int quad = lane >> 4, l15 = lane & 15;
    int wm = wid >> 1, wn = wid & 1;
    int n0 = blockIdx.x * 128, c0 = blockIdx.y * 128, b = blockIdx.z;
    const u16* asrc = Weffb + ((size_t)b * 256 + c0) * 512;
    const u16* bsrc = qT + ((size_t)b * N_ + n0) * 512;

    f32x4 acc[4][4];
#pragma unroll
    for (int i = 0; i < 4; i++)
#pragma unroll
        for (int j = 0; j < 4; j++) acc[i][j] = (f32x4){0.f, 0.f, 0.f, 0.f};

    int srow = lane >> 3;
    int sc8  = ((lane & 7) ^ srow) * 8;

    for (int kc = 0; kc < 8; kc++) {
        int koff = kc * 64 + sc8;
#pragma unroll
        for (int i = 0; i < 4; i++) {
            int row = (wid * 4 + i) * 8 + srow;
            gl_lds16(&asrc[(size_t)row * 512 + koff], &WS[(wid * 4 + i) * 512]);
            gl_lds16(&bsrc[(size_t)row * 512 + koff], &XS[(wid * 4 + i) * 512]);
        }
        __syncthreads();
#pragma unroll
        for (int ks = 0; ks < 2; ks++) {
            int cc = ks * 4 + quad;
            s16x8 af[4], bf[4];
#pragma unroll
            for (int f = 0; f < 4; f++) {
                int ar = wm * 64 + f * 16 + l15;
                int br = wn * 64 + f * 16 + l15;
                af[f] = *(const s16x8*)&WS[ar * 64 + ((cc ^ (ar & 7)) * 8)];
                bf[f] = *(const s16x8*)&XS[br * 64 + ((cc ^ (br & 7)) * 8)];
            }
#pragma unroll
            for (int i = 0; i < 4; i++)
#pragma unroll
                for (int j = 0; j < 4; j++)
                    acc[i][j] = __builtin_amdgcn_mfma_f32_16x16x32_bf16(af[i], bf[j], acc[i][j], 0, 0, 0);
        }
        __syncthreads();
    }
#pragma unroll
    for (int mf = 0; mf < 4; mf++)
#pragma unroll
        for (int r = 0; r < 4; r++) {
            int c = c0 + wm * 64 + mf * 16 + quad * 4 + r;
            float bov = bo[c];
#pragma unroll
            for (int nf = 0; nf < 4; nf++)
                out[((size_t)b * 256 + c) * N_ + n0 + wn * 64 + nf * 16 + l15] = acc[mf][nf][r] + bov;
        }
}

extern "C" void kernel_launch(void* const* d_in, const int* in_sizes, int n_in,
                              void* d_out, int out_size, void* d_ws, size_t ws_size,
                              hipStream_t stream) {
    const float* x   = (const float*)d_in[0];
    const float* wq  = (const float*)d_in[1];
    const float* bq  = (const float*)d_in[2];
    const float* wk  = (const float*)d_in[3];
    const float* bk  = (const float*)d_in[4];
    const float* wv  = (const float*)d_in[5];
    const float* bv  = (const float*)d_in[6];
    const float* wo  = (const float*)d_in[7];
    const float* bo  = (const float*)d_in[8];
    const float* gq  = (const float*)d_in[9];
    const float* beq = (const float*)d_in[10];
    const float* gk  = (const float*)d_in[11];
    const float* bek = (const float*)d_in[12];
    const float* gv  = (const float*)d_in[13];
    const float* bev = (const float*)d_in[14];
    float* out = (float*)d_out;

    char* ws = (char*)d_ws;
    // xT   [0, 33554432)            bf16 [B][N][C]
    // wb   [33554432, 34340864)     bf16 [3][512][256]
    // eKb  [34340864, 101449728)    bf16 blocked tiles (dead after ctx)
    // qT   [34340864, 101449728)    bf16 [B][N][512]  (aliases eKb)
    // vbb  [101449728, 168558592)   bf16 blocked tiles
    // ctx  [168558592, 169082880)   fp32 [B][8][64][64]
    // rs   [169082880, 169091072)   fp32 [B][512]
    // Weff [169091072, 170139648)   bf16 [B][256][512]
    u16* xT      = (u16*)(ws);
    u16* wb      = (u16*)(ws + 33554432ULL);
    u16* eKb     = (u16*)(ws + 34340864ULL);
    u16* qT      = (u16*)(ws + 34340864ULL);
    u16* vbb     = (u16*)(ws + 101449728ULL);
    float* ctx_a = (float*)(ws + 168558592ULL);
    float* rs    = (float*)(ws + 169082880ULL);
    u16* Weffb   = (u16*)(ws + 169091072ULL);

    cvtw_kernel<<<dim3(512, 3), 256, 0, stream>>>(wq, wk, wv, wb);
    transpose_kernel<<<dim3(256, 4, 4), 256, 0, stream>>>(x, xT);
    zero_kernel<<<dim3(520), 256, 0, stream>>>(ctx_a, 133120);  // ctx + rs contiguous

    kv_kernel<<<dim3(128, 8, 4), 256, 0, stream>>>(
        xT, wb, bk, bv, gk, bek, gv, bev, eKb, vbb, rs);

    ctx_kernel<<<dim3(16, 8, 4), 256, 0, stream>>>(eKb, vbb, ctx_a);

    q_kernel<<<dim3(128, 4, 4), 256, 0, stream>>>(xT, wb, bq, gq, beq, qT);

    weff_kernel<<<dim3(8, 4, 4), 256, 0, stream>>>(ctx_a, rs, wo, Weffb);

    out_kernel<<<dim3(128, 2, 4), 256, 0, stream>>>(Weffb, qT, bo, out);
}